// Round 4
// baseline (514.730 us; speedup 1.0000x reference)
//
#include <hip/hip_runtime.h>
#include <math.h>

// ---------------------------------------------------------------------------
// FusionMoE R4: barrier-free K-loops (A and B direct global->VGPR with ring
// prefetch; N is small so no LDS staging needed for GEMM). Expert pipeline
// mega-fused into one kernel (h1/h2 in LDS, no HBM round-trips). GELU via
// sigmoid-form approx (erff was ~17us device-wide).
// ---------------------------------------------------------------------------

typedef unsigned short u16;
typedef unsigned int u32;
typedef __attribute__((ext_vector_type(8))) short bf16x8;
typedef __attribute__((ext_vector_type(4))) float f32x4;

__device__ __forceinline__ float bf2f(u16 u) {
    union { u32 i; float f; } v; v.i = ((u32)u) << 16; return v.f;
}
__device__ __forceinline__ u16 f2bf(float f) {  // RNE
    union { float f; u32 i; } v; v.f = f;
    u32 x = v.i;
    return (u16)((x + 0x7fffu + ((x >> 16) & 1u)) >> 16);
}
// gelu(x) = x * sigmoid(1.59577x + 0.0713548x^3)  (tanh-form identity)
__device__ __forceinline__ float gelu_fast(float x) {
    float t = x * (1.59576912f + 0.07135481f * x * x);
    return x / (1.f + __expf(-t));
}
// pack two f32 (bit-truncate) into one u32 of two bf16 (f0 low, f1 high)
__device__ __forceinline__ u32 pk2(u32 f0, u32 f1) {
    return __builtin_amdgcn_perm(f1, f0, 0x07060302);
}

// ---------------------------------------------------------------------------
// K0: prep — weight transposes to bf16 + lbacc zero
// ---------------------------------------------------------------------------
#define SEG_WF  409600
#define SEG_W1  524288
#define SEG_W2  524288
#define SEG_W3  262144
#define PREP_ITEMS (SEG_WF + SEG_W1 + SEG_W2 + SEG_W3 + 8)

__global__ __launch_bounds__(256) void prep_kernel(
    const float* __restrict__ Wf, const float* __restrict__ W1, const float* __restrict__ W2,
    const float* __restrict__ W3,
    u16* __restrict__ wft, u16* __restrict__ w1t, u16* __restrict__ w2t, u16* __restrict__ w3t,
    float* __restrict__ lbacc) {
    int idx = blockIdx.x * 256 + threadIdx.x;
    if (idx < SEG_WF) {  // WfT[n<256][k<1600] = Wf[k][n]
        int n = idx / 1600, k = idx % 1600;
        wft[idx] = f2bf(Wf[(size_t)k * 256 + n]);
        return;
    }
    idx -= SEG_WF;
    if (idx < SEG_W1) {  // W1T[e][n<512][k<256] = W1[e][k][n]
        int e = idx >> 17, r = idx & 131071;
        int n = r >> 8, k = r & 255;
        w1t[idx] = f2bf(W1[(size_t)e * 131072 + (size_t)k * 512 + n]);
        return;
    }
    idx -= SEG_W1;
    if (idx < SEG_W2) {  // W2T[e][n<256][k<512] = W2[e][k][n]
        int e = idx >> 17, r = idx & 131071;
        int n = r >> 9, k = r & 511;
        w2t[idx] = f2bf(W2[(size_t)e * 131072 + (size_t)k * 256 + n]);
        return;
    }
    idx -= SEG_W2;
    if (idx < SEG_W3) {  // W3T[e][n<256][k<256] = W3[e][k][n]
        int e = idx >> 16, r = idx & 65535;
        int n = r >> 8, k = r & 255;
        w3t[idx] = f2bf(W3[(size_t)e * 65536 + (size_t)k * 256 + n]);
        return;
    }
    idx -= SEG_W3;
    if (idx < 8) lbacc[idx] = 0.0f;
}

// ---------------------------------------------------------------------------
// K1: fusion — 32x256 tile, 50 kits BK=32, NO LDS in K-loop, no barriers.
// A fp32 direct->VGPR ring-3 (lookahead 2), B bf16 direct->VGPR ring-2.
// Epilogue: bias+LN+GELU -> xbf, fused gate -> wr + lb atomics.
// ---------------------------------------------------------------------------
__global__ __launch_bounds__(256) void fusion_kernel(
    const float* __restrict__ vis, const float* __restrict__ lang, const float* __restrict__ state,
    const u16* __restrict__ BT, const float* __restrict__ bfv_, const float* __restrict__ gf,
    const float* __restrict__ bfln, const float* __restrict__ Wg,
    u16* __restrict__ xbf, float* __restrict__ wr, float* __restrict__ lbacc) {
    __shared__ float2 red[128];
    __shared__ float muv[32], rsv[32];
    __shared__ float gred[512];
    __shared__ float sacc[8];
    int tid = threadIdx.x, w = tid >> 6, lane = tid & 63, quad = lane >> 4, l16 = lane & 15;
    int m0 = blockIdx.x * 32;
    f32x4 acc[2][4] = {};
    uint4 aR[3][2][2];
    uint4 bR[2][4];

    auto loadA = [&](int k, int s) {
        const float* base; int ld;
        if (k < 24)      { base = vis + k * 32;          ld = 768; }
        else if (k < 48) { base = lang + (k - 24) * 32;  ld = 768; }
        else             { base = state + (k - 48) * 32; ld = 64; }
#pragma unroll
        for (int mt = 0; mt < 2; ++mt) {
            const float* p = base + (size_t)(m0 + mt * 16 + l16) * ld + quad * 8;
            aR[s][mt][0] = *(const uint4*)p;
            aR[s][mt][1] = *(const uint4*)(p + 4);
        }
    };
    auto loadB = [&](int k, int s) {
#pragma unroll
        for (int nt = 0; nt < 4; ++nt) {
            int n = w * 64 + nt * 16 + l16;
            bR[s][nt] = *(const uint4*)(BT + (size_t)n * 1600 + k * 32 + quad * 8);
        }
    };
    auto comp = [&](int sa, int sb) {
        bf16x8 av[2];
#pragma unroll
        for (int mt = 0; mt < 2; ++mt) {
            union { u32 u[4]; bf16x8 v; } pk;
            pk.u[0] = pk2(aR[sa][mt][0].x, aR[sa][mt][0].y);
            pk.u[1] = pk2(aR[sa][mt][0].z, aR[sa][mt][0].w);
            pk.u[2] = pk2(aR[sa][mt][1].x, aR[sa][mt][1].y);
            pk.u[3] = pk2(aR[sa][mt][1].z, aR[sa][mt][1].w);
            av[mt] = pk.v;
        }
#pragma unroll
        for (int nt = 0; nt < 4; ++nt) {
            union { uint4 u; bf16x8 v; } bb; bb.u = bR[sb][nt];
#pragma unroll
            for (int mt = 0; mt < 2; ++mt)
                acc[mt][nt] = __builtin_amdgcn_mfma_f32_16x16x32_bf16(av[mt], bb.v, acc[mt][nt], 0, 0, 0);
        }
    };

    loadA(0, 0); loadA(1, 1); loadB(0, 0);
#pragma unroll
    for (int k = 0; k < 50; ++k) {
        if (k + 2 < 50) loadA(k + 2, (k + 2) % 3);
        if (k + 1 < 50) loadB(k + 1, (k + 1) & 1);
        comp(k % 3, k & 1);
    }

    // ---- epilogue: bias, LN, GELU, xbf store, fused gate (R2-verified) ----
    float bv[4], gvv[4], blv[4]; float4 wgv[4];
#pragma unroll
    for (int nt = 0; nt < 4; ++nt) {
        int col = w * 64 + nt * 16 + l16;
        bv[nt] = bfv_[col]; gvv[nt] = gf[col]; blv[nt] = bfln[col];
        wgv[nt] = *(const float4*)(Wg + col * 4);
    }
    if (tid < 8) sacc[tid] = 0.f;
#pragma unroll
    for (int mt = 0; mt < 2; ++mt)
#pragma unroll
        for (int r = 0; r < 4; ++r) {
            float ss = 0.f, qq = 0.f;
#pragma unroll
            for (int nt = 0; nt < 4; ++nt) {
                float v = acc[mt][nt][r] + bv[nt];
                acc[mt][nt][r] = v;
                ss += v; qq += v * v;
            }
#pragma unroll
            for (int d = 1; d < 16; d <<= 1) { ss += __shfl_xor(ss, d); qq += __shfl_xor(qq, d); }
            if (l16 == 0) red[w * 32 + mt * 16 + quad * 4 + r] = make_float2(ss, qq);
        }
    __syncthreads();
    if (tid < 32) {
        float ss = 0.f, qq = 0.f;
#pragma unroll
        for (int ww = 0; ww < 4; ++ww) { float2 t = red[ww * 32 + tid]; ss += t.x; qq += t.y; }
        float mu = ss * (1.f / 256.f);
        float var = qq * (1.f / 256.f) - mu * mu;
        muv[tid] = mu;
        rsv[tid] = 1.f / sqrtf(var + 1e-5f);
    }
    __syncthreads();
#pragma unroll
    for (int mt = 0; mt < 2; ++mt)
#pragma unroll
        for (int r = 0; r < 4; ++r) {
            int rl = mt * 16 + quad * 4 + r;
            float mu = muv[rl], rs = rsv[rl];
#pragma unroll
            for (int nt = 0; nt < 4; ++nt) {
                int col = w * 64 + nt * 16 + l16;
                float t = (acc[mt][nt][r] - mu) * rs * gvv[nt] + blv[nt];
                float g = gelu_fast(t);
                acc[mt][nt][r] = g;
                xbf[(size_t)(m0 + rl) * 256 + col] = f2bf(g);
            }
        }
#pragma unroll
    for (int mt = 0; mt < 2; ++mt)
#pragma unroll
        for (int r = 0; r < 4; ++r) {
            int rl = mt * 16 + quad * 4 + r;
            float p0 = 0.f, p1 = 0.f, p2 = 0.f, p3 = 0.f;
#pragma unroll
            for (int nt = 0; nt < 4; ++nt) {
                float g = acc[mt][nt][r];
                p0 += g * wgv[nt].x; p1 += g * wgv[nt].y;
                p2 += g * wgv[nt].z; p3 += g * wgv[nt].w;
            }
#pragma unroll
            for (int d = 1; d < 16; d <<= 1) {
                p0 += __shfl_xor(p0, d); p1 += __shfl_xor(p1, d);
                p2 += __shfl_xor(p2, d); p3 += __shfl_xor(p3, d);
            }
            if (l16 == 0) {
                float* gp = gred + w * 128 + rl * 4;
                gp[0] = p0; gp[1] = p1; gp[2] = p2; gp[3] = p3;
            }
        }
    __syncthreads();
    if (tid < 32) {
        int row = tid;
        float lg[4];
#pragma unroll
        for (int e = 0; e < 4; ++e)
            lg[e] = gred[row * 4 + e] + gred[128 + row * 4 + e] +
                    gred[256 + row * 4 + e] + gred[384 + row * 4 + e];
        float mx = fmaxf(fmaxf(lg[0], lg[1]), fmaxf(lg[2], lg[3]));
        float ex[4]; float Z = 0.f;
#pragma unroll
        for (int e = 0; e < 4; ++e) { ex[e] = expf(lg[e] - mx); Z += ex[e]; }
        int i0 = 0; float v0 = lg[0];
#pragma unroll
        for (int e = 1; e < 4; ++e) if (lg[e] > v0) { v0 = lg[e]; i0 = e; }
        int i1 = -1; float v1 = -1e30f;
#pragma unroll
        for (int e = 0; e < 4; ++e) if (e != i0 && lg[e] > v1) { v1 = lg[e]; i1 = e; }
        float t = expf(v1 - v0);
        float wA = 1.f / (1.f + t), wB = t / (1.f + t);
        float w4[4] = {0.f, 0.f, 0.f, 0.f};
        w4[i0] = wA; w4[i1] = wB;
#pragma unroll
        for (int e = 0; e < 4; ++e) wr[(size_t)(m0 + row) * 4 + e] = w4[e];
#pragma unroll
        for (int e = 0; e < 4; ++e) atomicAdd(&sacc[e], ex[e] / Z);
        atomicAdd(&sacc[4 + i0], 1.f);
        atomicAdd(&sacc[4 + i1], 1.f);
    }
    __syncthreads();
    if (tid < 8) atomicAdd(lbacc + tid, sacc[tid]);
}

// ---------------------------------------------------------------------------
// K2: mega expert kernel — per 32-row tile, loop e: x@W1->gelu->h1(LDS) ->
// h1@W2->gelu->h2(LDS) -> h2@W3 + b3 + x -> LN -> *eg+eb -> oacc += we*y.
// B direct global->VGPR ring-2 (L2-hot weights). ~5 barriers per expert.
// ---------------------------------------------------------------------------
#define LDX  264
#define LDH1 520
#define LDH2 264

__global__ __launch_bounds__(256) void moe_kernel(
    const u16* __restrict__ xbf, const u16* __restrict__ W1T, const u16* __restrict__ W2T,
    const u16* __restrict__ W3T, const float* __restrict__ b1, const float* __restrict__ b2,
    const float* __restrict__ b3, const float* __restrict__ eg, const float* __restrict__ eb,
    const float* __restrict__ wr, const float* __restrict__ lbacc, float* __restrict__ outp) {
    __shared__ __align__(16) u16 xs[32 * LDX];    // 16.5 KB
    __shared__ __align__(16) u16 h1s[32 * LDH1];  // 32.5 KB
    __shared__ __align__(16) u16 h2s[32 * LDH2];  // 16.5 KB
    __shared__ float wl[128];
    __shared__ float2 red[128];
    __shared__ float muv[32], rsv[32];
    int tid = threadIdx.x, w = tid >> 6, lane = tid & 63, quad = lane >> 4, l16 = lane & 15;
    int m0 = blockIdx.x * 32;
    if (blockIdx.x == 0 && tid == 0) {            // lb_loss (lbacc ready)
        float lb = 0.f;
#pragma unroll
        for (int e = 0; e < 4; ++e)
            lb += (lbacc[4 + e] / 32768.f) * (lbacc[e] / 16384.f);
        outp[4194304] = 4.f * lb;
    }
#pragma unroll
    for (int i = 0; i < 4; ++i) {
        int s = i * 256 + tid, r = s >> 5, c = s & 31;
        *(uint4*)(xs + r * LDX + c * 8) = *(const uint4*)(xbf + (size_t)(m0 + r) * 256 + c * 8);
    }
    if (tid < 128) wl[tid] = wr[(size_t)m0 * 4 + tid];
    __syncthreads();

    f32x4 oacc[2][4] = {};
#pragma unroll 1
    for (int e = 0; e < 4; ++e) {
        // ---------- layer1: C1[32][128/wave], K=256, 8 kits ----------
        {
            f32x4 a1[2][8] = {};
            const u16* Bg = W1T + (size_t)e * 131072 + (size_t)(w * 128) * 256;
            uint4 bR[2][8];
#pragma unroll
            for (int nt = 0; nt < 8; ++nt)
                bR[0][nt] = *(const uint4*)(Bg + (size_t)(nt * 16 + l16) * 256 + quad * 8);
#pragma unroll
            for (int kit = 0; kit < 8; ++kit) {
                if (kit + 1 < 8) {
#pragma unroll
                    for (int nt = 0; nt < 8; ++nt)
                        bR[(kit + 1) & 1][nt] = *(const uint4*)(Bg + (size_t)(nt * 16 + l16) * 256 + (kit + 1) * 32 + quad * 8);
                }
                bf16x8 av[2];
#pragma unroll
                for (int mt = 0; mt < 2; ++mt)
                    av[mt] = *(const bf16x8*)(xs + (mt * 16 + l16) * LDX + kit * 32 + quad * 8);
#pragma unroll
                for (int nt = 0; nt < 8; ++nt) {
                    union { uint4 u; bf16x8 v; } bb; bb.u = bR[kit & 1][nt];
#pragma unroll
                    for (int mt = 0; mt < 2; ++mt)
                        a1[mt][nt] = __builtin_amdgcn_mfma_f32_16x16x32_bf16(av[mt], bb.v, a1[mt][nt], 0, 0, 0);
                }
            }
            __syncthreads();   // (1) prior h1s readers done / scratch reuse guard
            float b1v[8];
#pragma unroll
            for (int nt = 0; nt < 8; ++nt) b1v[nt] = b1[e * 512 + w * 128 + nt * 16 + l16];
#pragma unroll
            for (int mt = 0; mt < 2; ++mt)
#pragma unroll
                for (int nt = 0; nt < 8; ++nt)
#pragma unroll
                    for (int r = 0; r < 4; ++r) {
                        float v = gelu_fast(a1[mt][nt][r] + b1v[nt]);
                        float o = __shfl_xor(v, 1);
                        u16 hA = f2bf(v), hB = f2bf(o);
                        u32 dw = (l16 & 1) ? ((u32)hB | ((u32)hA << 16)) : ((u32)hA | ((u32)hB << 16));
                        if (!(l16 & 1))
                            *(u32*)(h1s + (mt * 16 + quad * 4 + r) * LDH1 + w * 128 + nt * 16 + l16) = dw;
                    }
        }
        __syncthreads();       // (2) h1 ready

        // ---------- layer2: C2[32][64/wave], K=512, 16 kits ----------
        {
            f32x4 a2[2][4] = {};
            const u16* Bg = W2T + (size_t)e * 131072 + (size_t)(w * 64) * 512;
            uint4 bR[2][4];
#pragma unroll
            for (int nt = 0; nt < 4; ++nt)
                bR[0][nt] = *(const uint4*)(Bg + (size_t)(nt * 16 + l16) * 512 + quad * 8);
#pragma unroll
            for (int kit = 0; kit < 16; ++kit) {
                if (kit + 1 < 16) {
#pragma unroll
                    for (int nt = 0; nt < 4; ++nt)
                        bR[(kit + 1) & 1][nt] = *(const uint4*)(Bg + (size_t)(nt * 16 + l16) * 512 + (kit + 1) * 32 + quad * 8);
                }
                bf16x8 av[2];
#pragma unroll
                for (int mt = 0; mt < 2; ++mt)
                    av[mt] = *(const bf16x8*)(h1s + (mt * 16 + l16) * LDH1 + kit * 32 + quad * 8);
#pragma unroll
                for (int nt = 0; nt < 4; ++nt) {
                    union { uint4 u; bf16x8 v; } bb; bb.u = bR[kit & 1][nt];
#pragma unroll
                    for (int mt = 0; mt < 2; ++mt)
                        a2[mt][nt] = __builtin_amdgcn_mfma_f32_16x16x32_bf16(av[mt], bb.v, a2[mt][nt], 0, 0, 0);
                }
            }
            float b2v[4];
#pragma unroll
            for (int nt = 0; nt < 4; ++nt) b2v[nt] = b2[e * 256 + w * 64 + nt * 16 + l16];
#pragma unroll
            for (int mt = 0; mt < 2; ++mt)
#pragma unroll
                for (int nt = 0; nt < 4; ++nt)
#pragma unroll
                    for (int r = 0; r < 4; ++r) {
                        float v = gelu_fast(a2[mt][nt][r] + b2v[nt]);
                        float o = __shfl_xor(v, 1);
                        u16 hA = f2bf(v), hB = f2bf(o);
                        u32 dw = (l16 & 1) ? ((u32)hB | ((u32)hA << 16)) : ((u32)hA | ((u32)hB << 16));
                        if (!(l16 & 1))
                            *(u32*)(h2s + (mt * 16 + quad * 4 + r) * LDH2 + w * 64 + nt * 16 + l16) = dw;
                    }
        }
        __syncthreads();       // (3) h2 ready

        // ---------- layer3 + LN + combine: C3[32][64/wave], K=256 ----------
        {
            f32x4 a3[2][4] = {};
            const u16* Bg = W3T + (size_t)e * 65536 + (size_t)(w * 64) * 256;
            uint4 bR[2][4];
#pragma unroll
            for (int nt = 0; nt < 4; ++nt)
                bR[0][nt] = *(const uint4*)(Bg + (size_t)(nt * 16 + l16) * 256 + quad * 8);
#pragma unroll
            for (int kit = 0; kit < 8; ++kit) {
                if (kit + 1 < 8) {
#pragma unroll
                    for (int nt = 0; nt < 4; ++nt)
                        bR[(kit + 1) & 1][nt] = *(const uint4*)(Bg + (size_t)(nt * 16 + l16) * 256 + (kit + 1) * 32 + quad * 8);
                }
                bf16x8 av[2];
#pragma unroll
                for (int mt = 0; mt < 2; ++mt)
                    av[mt] = *(const bf16x8*)(h2s + (mt * 16 + l16) * LDH2 + kit * 32 + quad * 8);
#pragma unroll
                for (int nt = 0; nt < 4; ++nt) {
                    union { uint4 u; bf16x8 v; } bb; bb.u = bR[kit & 1][nt];
#pragma unroll
                    for (int mt = 0; mt < 2; ++mt)
                        a3[mt][nt] = __builtin_amdgcn_mfma_f32_16x16x32_bf16(av[mt], bb.v, a3[mt][nt], 0, 0, 0);
                }
            }
            float b3v[4], egv[4], ebv[4];
#pragma unroll
            for (int nt = 0; nt < 4; ++nt) {
                int col = w * 64 + nt * 16 + l16;
                b3v[nt] = b3[e * 256 + col]; egv[nt] = eg[e * 256 + col]; ebv[nt] = eb[e * 256 + col];
            }
#pragma unroll
            for (int mt = 0; mt < 2; ++mt)
#pragma unroll
                for (int r = 0; r < 4; ++r) {
                    int rl = mt * 16 + quad * 4 + r;
                    float ss = 0.f, qq = 0.f;
#pragma unroll
                    for (int nt = 0; nt < 4; ++nt) {
                        int col = w * 64 + nt * 16 + l16;
                        float v = a3[mt][nt][r] + b3v[nt] + bf2f(xs[rl * LDX + col]);
                        a3[mt][nt][r] = v;
                        ss += v; qq += v * v;
                    }
#pragma unroll
                    for (int d = 1; d < 16; d <<= 1) { ss += __shfl_xor(ss, d); qq += __shfl_xor(qq, d); }
                    if (l16 == 0) red[w * 32 + rl] = make_float2(ss, qq);
                }
            __syncthreads();   // (4)
            if (tid < 32) {
                float ss = 0.f, qq = 0.f;
#pragma unroll
                for (int ww = 0; ww < 4; ++ww) { float2 t = red[ww * 32 + tid]; ss += t.x; qq += t.y; }
                float mu = ss * (1.f / 256.f);
                float var = qq * (1.f / 256.f) - mu * mu;
                muv[tid] = mu;
                rsv[tid] = 1.f / sqrtf(var + 1e-5f);
            }
            __syncthreads();   // (5)
#pragma unroll
            for (int mt = 0; mt < 2; ++mt)
#pragma unroll
                for (int r = 0; r < 4; ++r) {
                    int rl = mt * 16 + quad * 4 + r;
                    float mu = muv[rl], rs = rsv[rl], we = wl[rl * 4 + e];
#pragma unroll
                    for (int nt = 0; nt < 4; ++nt) {
                        float y = (a3[mt][nt][r] - mu) * rs * egv[nt] + ebv[nt];
                        oacc[mt][nt][r] += we * y;
                    }
                }
        }
    }
#pragma unroll
    for (int mt = 0; mt < 2; ++mt)
#pragma unroll
        for (int r = 0; r < 4; ++r) {
            int rl = mt * 16 + quad * 4 + r;
#pragma unroll
            for (int nt = 0; nt < 4; ++nt) {
                int col = w * 64 + nt * 16 + l16;
                outp[(size_t)(m0 + rl) * 256 + col] = oacc[mt][nt][r];
            }
        }
}

// ---------------------------------------------------------------------------
extern "C" void kernel_launch(void* const* d_in, const int* in_sizes, int n_in,
                              void* d_out, int out_size, void* d_ws, size_t ws_size,
                              hipStream_t stream) {
    const float* vis   = (const float*)d_in[0];
    const float* lang  = (const float*)d_in[1];
    const float* state = (const float*)d_in[2];
    const float* Wf    = (const float*)d_in[3];
    const float* bf_   = (const float*)d_in[4];
    const float* gf    = (const float*)d_in[5];
    const float* bfln  = (const float*)d_in[6];
    const float* Wg    = (const float*)d_in[7];
    const float* W1    = (const float*)d_in[8];
    const float* b1    = (const float*)d_in[9];
    const float* W2    = (const float*)d_in[10];
    const float* b2    = (const float*)d_in[11];
    const float* W3    = (const float*)d_in[12];
    const float* b3    = (const float*)d_in[13];
    const float* eg    = (const float*)d_in[14];
    const float* eb    = (const float*)d_in[15];
    float* outp = (float*)d_out;

    char* ws = (char*)d_ws;
    size_t off = 0;
    float* lbacc = (float*)(ws + off); off += 256;
    u16* WFT  = (u16*)(ws + off); off += 819200UL;     // WfT [256][1600]
    u16* W1T  = (u16*)(ws + off); off += 1048576UL;    // [E][512][256]
    u16* W2T  = (u16*)(ws + off); off += 1048576UL;    // [E][256][512]
    u16* W3T  = (u16*)(ws + off); off += 524288UL;     // [E][256][256]
    u16* XBF  = (u16*)(ws + off); off += 8388608UL;    // x bf16 [B][256]
    float* WR = (float*)(ws + off); off += 262144UL;   // gate weights [B][4]
    if (ws_size < off) return;

    int prep_blocks = (PREP_ITEMS + 255) / 256;
    prep_kernel<<<prep_blocks, 256, 0, stream>>>(Wf, W1, W2, W3, WFT, W1T, W2T, W3T, lbacc);
    fusion_kernel<<<512, 256, 0, stream>>>(vis, lang, state, WFT, bf_, gf, bfln, Wg,
                                           XBF, WR, lbacc);
    moe_kernel<<<512, 256, 0, stream>>>(XBF, W1T, W2T, W3T, b1, b2, b3, eg, eb,
                                        WR, lbacc, outp);
}

// Round 5
// 342.571 us; speedup vs baseline: 1.5025x; 1.5025x over previous
//
#include <hip/hip_runtime.h>
#include <math.h>

// ---------------------------------------------------------------------------
// FusionMoE R5: back to the R2-proven LDS-staged structure (BK=64 layouts,
// measured 0 bank conflicts), now with double-buffered staging and ONE
// __syncthreads per kit (stage k+1 in flight during compute k). 3-kernel MoE
// with proper grids. gelu_fast. Residual x in registers in combine.
// ---------------------------------------------------------------------------

typedef unsigned short u16;
typedef unsigned int u32;
typedef __attribute__((ext_vector_type(8))) short bf16x8;
typedef __attribute__((ext_vector_type(4))) float f32x4;

__device__ __forceinline__ float bf2f(u16 u) {
    union { u32 i; float f; } v; v.i = ((u32)u) << 16; return v.f;
}
__device__ __forceinline__ u16 f2bf(float f) {  // RNE
    union { float f; u32 i; } v; v.f = f;
    u32 x = v.i;
    return (u16)((x + 0x7fffu + ((x >> 16) & 1u)) >> 16);
}
// gelu(x) = x * sigmoid(1.59577x + 0.0713548x^3)
__device__ __forceinline__ float gelu_fast(float x) {
    float t = x * (1.59576912f + 0.07135481f * x * x);
    return x / (1.f + __expf(-t));
}
// pack two f32 (bit-truncate) into one u32 of two bf16
__device__ __forceinline__ u32 pk2(u32 f0, u32 f1) {
    return __builtin_amdgcn_perm(f1, f0, 0x07060302);
}

typedef __attribute__((address_space(1))) void GV;
typedef __attribute__((address_space(3))) void SV;
__device__ __forceinline__ void gldlds(const void* g, void* l) {
    __builtin_amdgcn_global_load_lds((GV*)g, (SV*)l, 16, 0, 0);
}

// ---------------------------------------------------------------------------
// K0: prep — weight transposes to bf16 + lbacc zero
// ---------------------------------------------------------------------------
#define SEG_WF  409600
#define SEG_W1  524288
#define SEG_W2  524288
#define SEG_W3  262144
#define PREP_ITEMS (SEG_WF + SEG_W1 + SEG_W2 + SEG_W3 + 8)

__global__ __launch_bounds__(256) void prep_kernel(
    const float* __restrict__ Wf, const float* __restrict__ W1, const float* __restrict__ W2,
    const float* __restrict__ W3,
    u16* __restrict__ wft, u16* __restrict__ w1t, u16* __restrict__ w2t, u16* __restrict__ w3t,
    float* __restrict__ lbacc) {
    int idx = blockIdx.x * 256 + threadIdx.x;
    if (idx < SEG_WF) {  // WfT[n<256][k<1600] = Wf[k][n]
        int n = idx / 1600, k = idx % 1600;
        wft[idx] = f2bf(Wf[(size_t)k * 256 + n]);
        return;
    }
    idx -= SEG_WF;
    if (idx < SEG_W1) {  // W1T[e][n<512][k<256] = W1[e][k][n]
        int e = idx >> 17, r = idx & 131071;
        int n = r >> 8, k = r & 255;
        w1t[idx] = f2bf(W1[(size_t)e * 131072 + (size_t)k * 512 + n]);
        return;
    }
    idx -= SEG_W1;
    if (idx < SEG_W2) {  // W2T[e][n<256][k<512] = W2[e][k][n]
        int e = idx >> 17, r = idx & 131071;
        int n = r >> 9, k = r & 511;
        w2t[idx] = f2bf(W2[(size_t)e * 131072 + (size_t)k * 256 + n]);
        return;
    }
    idx -= SEG_W2;
    if (idx < SEG_W3) {  // W3T[e][n<256][k<256] = W3[e][k][n]
        int e = idx >> 16, r = idx & 65535;
        int n = r >> 8, k = r & 255;
        w3t[idx] = f2bf(W3[(size_t)e * 65536 + (size_t)k * 256 + n]);
        return;
    }
    idx -= SEG_W3;
    if (idx < 8) lbacc[idx] = 0.0f;
}

// ---------------------------------------------------------------------------
// K1: fusion — 32x256 tile, 25 kits BK=64, dbuf LDS (A fp32 + B bf16),
// 1 barrier/kit. Epilogue: bias+LN+GELU -> xbf, fused gate -> wr + lbacc.
// ---------------------------------------------------------------------------
__global__ __launch_bounds__(256) void fusion_kernel(
    const float* __restrict__ vis, const float* __restrict__ lang, const float* __restrict__ state,
    const u16* __restrict__ BT, const float* __restrict__ bfv_, const float* __restrict__ gf,
    const float* __restrict__ bfln, const float* __restrict__ Wg,
    u16* __restrict__ xbf, float* __restrict__ wr, float* __restrict__ lbacc) {
    __shared__ __align__(16) u32 Af[2][2048];   // 2 x 8KB: 32 rows x 64 f32 (16B-chunk XOR-16)
    __shared__ __align__(16) u16 Bs[2][16384];  // 2 x 32KB: 256 n x 64 k (16B-chunk XOR-8)
    int tid = threadIdx.x, w = tid >> 6, lane = tid & 63, quad = lane >> 4, l16 = lane & 15;
    int m0 = blockIdx.x * 32;
    f32x4 acc[2][4] = {};

    auto stageAB = [&](int kit, int buf) {
        const float* base; int ld;
        if (kit < 12)      { base = vis + kit * 64;          ld = 768; }
        else if (kit < 24) { base = lang + (kit - 12) * 64;  ld = 768; }
        else               { base = state;                   ld = 64; }
        base += (size_t)m0 * ld;
#pragma unroll
        for (int i = 0; i < 2; ++i) {        // A: 512 chunks of 16B (4 f32)
            int s = i * 256 + tid, m = s >> 4, c = s & 15;
            gldlds(base + (size_t)m * ld + ((c ^ (m & 15)) << 2), &Af[buf][s * 4]);
        }
#pragma unroll
        for (int i = 0; i < 8; ++i) {        // B: 2048 chunks of 16B (8 bf16)
            int s = i * 256 + tid, n = s >> 3, c = s & 7;
            gldlds(BT + (size_t)n * 1600 + kit * 64 + ((c ^ (n & 7)) << 3), &Bs[buf][s * 8]);
        }
    };
    auto comp = [&](int buf) {
#pragma unroll
        for (int ks = 0; ks < 2; ++ks) {
            bf16x8 av[2];
#pragma unroll
            for (int mt = 0; mt < 2; ++mt) {
                int m = mt * 16 + l16;
                int c0 = ks * 8 + quad * 2;
                const u32* rowp = &Af[buf][m * 64];
                uint4 f0 = *(const uint4*)(rowp + ((c0 ^ (m & 15)) << 2));
                uint4 f1 = *(const uint4*)(rowp + (((c0 + 1) ^ (m & 15)) << 2));
                union { u32 u[4]; bf16x8 v; } pk;
                pk.u[0] = pk2(f0.x, f0.y); pk.u[1] = pk2(f0.z, f0.w);
                pk.u[2] = pk2(f1.x, f1.y); pk.u[3] = pk2(f1.z, f1.w);
                av[mt] = pk.v;
            }
#pragma unroll
            for (int nt = 0; nt < 4; ++nt) {
                int n = w * 64 + nt * 16 + l16;
                bf16x8 b = *(const bf16x8*)(&Bs[buf][n * 64 + (((ks * 4 + quad) ^ (n & 7)) << 3)]);
#pragma unroll
                for (int mt = 0; mt < 2; ++mt)
                    acc[mt][nt] = __builtin_amdgcn_mfma_f32_16x16x32_bf16(av[mt], b, acc[mt][nt], 0, 0, 0);
            }
        }
    };

    stageAB(0, 0);
    for (int k = 0; k < 25; ++k) {
        __syncthreads();
        if (k < 24) stageAB(k + 1, (k + 1) & 1);
        comp(k & 1);
    }
    // scratch lives in Bs[1]: last comp used buf 0; all Bs[1] reads finished
    // before the k=24 barrier -> race-free without an extra barrier.
    u32* SC = (u32*)(&Bs[1][0]);
    float2* red  = (float2*)SC;            // 128 float2
    float*  muv  = (float*)(SC + 256);     // 32
    float*  rsv  = (float*)(SC + 288);     // 32
    float*  gred = (float*)(SC + 512);     // 512
    float*  sacc = (float*)(SC + 1024);    // 8

    float bv[4], gvv[4], blv[4]; float4 wgv[4];
#pragma unroll
    for (int nt = 0; nt < 4; ++nt) {
        int col = w * 64 + nt * 16 + l16;
        bv[nt] = bfv_[col]; gvv[nt] = gf[col]; blv[nt] = bfln[col];
        wgv[nt] = *(const float4*)(Wg + col * 4);
    }
    if (tid < 8) sacc[tid] = 0.f;
#pragma unroll
    for (int mt = 0; mt < 2; ++mt)
#pragma unroll
        for (int r = 0; r < 4; ++r) {
            float ss = 0.f, qq = 0.f;
#pragma unroll
            for (int nt = 0; nt < 4; ++nt) {
                float v = acc[mt][nt][r] + bv[nt];
                acc[mt][nt][r] = v;
                ss += v; qq += v * v;
            }
#pragma unroll
            for (int d = 1; d < 16; d <<= 1) { ss += __shfl_xor(ss, d); qq += __shfl_xor(qq, d); }
            if (l16 == 0) red[w * 32 + mt * 16 + quad * 4 + r] = make_float2(ss, qq);
        }
    __syncthreads();
    if (tid < 32) {
        float ss = 0.f, qq = 0.f;
#pragma unroll
        for (int ww = 0; ww < 4; ++ww) { float2 t = red[ww * 32 + tid]; ss += t.x; qq += t.y; }
        float mu = ss * (1.f / 256.f);
        float var = qq * (1.f / 256.f) - mu * mu;
        muv[tid] = mu;
        rsv[tid] = 1.f / sqrtf(var + 1e-5f);
    }
    __syncthreads();
#pragma unroll
    for (int mt = 0; mt < 2; ++mt)
#pragma unroll
        for (int r = 0; r < 4; ++r) {
            int rl = mt * 16 + quad * 4 + r;
            float mu = muv[rl], rs = rsv[rl];
#pragma unroll
            for (int nt = 0; nt < 4; ++nt) {
                int col = w * 64 + nt * 16 + l16;
                float t = (acc[mt][nt][r] - mu) * rs * gvv[nt] + blv[nt];
                float g = gelu_fast(t);
                acc[mt][nt][r] = g;
                xbf[(size_t)(m0 + rl) * 256 + col] = f2bf(g);
            }
        }
#pragma unroll
    for (int mt = 0; mt < 2; ++mt)
#pragma unroll
        for (int r = 0; r < 4; ++r) {
            int rl = mt * 16 + quad * 4 + r;
            float p0 = 0.f, p1 = 0.f, p2 = 0.f, p3 = 0.f;
#pragma unroll
            for (int nt = 0; nt < 4; ++nt) {
                float g = acc[mt][nt][r];
                p0 += g * wgv[nt].x; p1 += g * wgv[nt].y;
                p2 += g * wgv[nt].z; p3 += g * wgv[nt].w;
            }
#pragma unroll
            for (int d = 1; d < 16; d <<= 1) {
                p0 += __shfl_xor(p0, d); p1 += __shfl_xor(p1, d);
                p2 += __shfl_xor(p2, d); p3 += __shfl_xor(p3, d);
            }
            if (l16 == 0) {
                float* gp = gred + w * 128 + rl * 4;
                gp[0] = p0; gp[1] = p1; gp[2] = p2; gp[3] = p3;
            }
        }
    __syncthreads();
    if (tid < 32) {
        int row = tid;
        float lg[4];
#pragma unroll
        for (int e = 0; e < 4; ++e)
            lg[e] = gred[row * 4 + e] + gred[128 + row * 4 + e] +
                    gred[256 + row * 4 + e] + gred[384 + row * 4 + e];
        float mx = fmaxf(fmaxf(lg[0], lg[1]), fmaxf(lg[2], lg[3]));
        float ex[4]; float Z = 0.f;
#pragma unroll
        for (int e = 0; e < 4; ++e) { ex[e] = expf(lg[e] - mx); Z += ex[e]; }
        int i0 = 0; float v0 = lg[0];
#pragma unroll
        for (int e = 1; e < 4; ++e) if (lg[e] > v0) { v0 = lg[e]; i0 = e; }
        int i1 = -1; float v1 = -1e30f;
#pragma unroll
        for (int e = 0; e < 4; ++e) if (e != i0 && lg[e] > v1) { v1 = lg[e]; i1 = e; }
        float t = expf(v1 - v0);
        float wA = 1.f / (1.f + t), wB = t / (1.f + t);
        float w4[4] = {0.f, 0.f, 0.f, 0.f};
        w4[i0] = wA; w4[i1] = wB;
#pragma unroll
        for (int e = 0; e < 4; ++e) wr[(size_t)(m0 + row) * 4 + e] = w4[e];
#pragma unroll
        for (int e = 0; e < 4; ++e) atomicAdd(&sacc[e], ex[e] / Z);
        atomicAdd(&sacc[4 + i0], 1.f);
        atomicAdd(&sacc[4 + i1], 1.f);
    }
    __syncthreads();
    if (tid < 8) atomicAdd(lbacc + tid, sacc[tid]);
}

// ---------------------------------------------------------------------------
// K2/K3: expert GEMM + bias + GELU. 64x128 tile, BK=64, dbuf, 1 barrier/kit.
// grid (m/64, n/128, E). 48KB LDS -> 3 blocks/CU.
// ---------------------------------------------------------------------------
template<int KITS>
__global__ __launch_bounds__(256) void expert_kernel(
    const u16* __restrict__ A, int lda, long aE,
    const u16* __restrict__ BT, long bE,
    const float* __restrict__ bias, int biasE,
    u16* __restrict__ outp, int ldo, long oE) {
    __shared__ __align__(16) u16 As[2][4096];   // 2 x 8KB: 64 m x 64 k
    __shared__ __align__(16) u16 Bs[2][8192];   // 2 x 16KB: 128 n x 64 k
    int tid = threadIdx.x, w = tid >> 6, lane = tid & 63, quad = lane >> 4, l16 = lane & 15;
    int m0 = blockIdx.x * 64;
    int n0 = blockIdx.y * 128;
    int e = blockIdx.z;
    const u16* Ag = A + (size_t)e * aE + (size_t)m0 * lda;
    const u16* Bg = BT + (size_t)e * bE + (size_t)n0 * lda;
    f32x4 acc[4][2] = {};

    auto stage = [&](int kit, int buf) {
#pragma unroll
        for (int i = 0; i < 2; ++i) {        // A: 512 slots (64 rows x 8 chunks)
            int s = i * 256 + tid, m = s >> 3, c = s & 7;
            gldlds(Ag + (size_t)m * lda + kit * 64 + ((c ^ (m & 7)) << 3), &As[buf][s * 8]);
        }
#pragma unroll
        for (int i = 0; i < 4; ++i) {        // B: 1024 slots (128 rows x 8 chunks)
            int s = i * 256 + tid, n = s >> 3, c = s & 7;
            gldlds(Bg + (size_t)n * lda + kit * 64 + ((c ^ (n & 7)) << 3), &Bs[buf][s * 8]);
        }
    };
    auto comp = [&](int buf) {
#pragma unroll
        for (int ks = 0; ks < 2; ++ks) {
            bf16x8 av[4];
#pragma unroll
            for (int mt = 0; mt < 4; ++mt) {
                int m = mt * 16 + l16;
                av[mt] = *(const bf16x8*)(&As[buf][m * 64 + (((ks * 4 + quad) ^ (m & 7)) << 3)]);
            }
#pragma unroll
            for (int nt = 0; nt < 2; ++nt) {
                int n = w * 32 + nt * 16 + l16;
                bf16x8 b = *(const bf16x8*)(&Bs[buf][n * 64 + (((ks * 4 + quad) ^ (n & 7)) << 3)]);
#pragma unroll
                for (int mt = 0; mt < 4; ++mt)
                    acc[mt][nt] = __builtin_amdgcn_mfma_f32_16x16x32_bf16(av[mt], b, acc[mt][nt], 0, 0, 0);
            }
        }
    };

    stage(0, 0);
    for (int k = 0; k < KITS; ++k) {
        __syncthreads();
        if (k + 1 < KITS) stage(k + 1, (k + 1) & 1);
        comp(k & 1);
    }

#pragma unroll
    for (int nt = 0; nt < 2; ++nt) {
        int col = n0 + w * 32 + nt * 16 + l16;
        float bvv = bias[e * biasE + col];
#pragma unroll
        for (int mt = 0; mt < 4; ++mt)
#pragma unroll
            for (int r = 0; r < 4; ++r) {
                int row = m0 + mt * 16 + quad * 4 + r;
                outp[(size_t)e * oE + (size_t)row * ldo + col] = f2bf(gelu_fast(acc[mt][nt][r] + bvv));
            }
    }
}

// ---------------------------------------------------------------------------
// K4: combine — 32x256 tile; linearized (expert,kit) dbuf loop (16 iters,
// 1 barrier/iter); A (h2) direct global->VGPR ring-2; residual x in regs;
// per-expert LN epilogue; lb_loss by block 0.
// ---------------------------------------------------------------------------
__global__ __launch_bounds__(256) void combine_kernel(
    const u16* __restrict__ h2, const u16* __restrict__ W3T,
    const float* __restrict__ b3, const float* __restrict__ eg, const float* __restrict__ eb,
    const u16* __restrict__ xbf, const float* __restrict__ wr,
    const float* __restrict__ lbacc, float* __restrict__ outp) {
    __shared__ __align__(16) u16 Bs[2][16384];  // 2 x 32KB: 256 n x 64 k
    __shared__ float wl[128];
    __shared__ float2 red[128];
    __shared__ float muv[32], rsv[32];
    int tid = threadIdx.x, w = tid >> 6, lane = tid & 63, quad = lane >> 4, l16 = lane & 15;
    int m0 = blockIdx.x * 32;
    if (blockIdx.x == 0 && tid == 0) {
        float lb = 0.f;
#pragma unroll
        for (int e = 0; e < 4; ++e)
            lb += (lbacc[4 + e] / 32768.f) * (lbacc[e] / 16384.f);
        outp[4194304] = 4.f * lb;
    }
    // residual x in registers (C-layout)
    u16 xr[2][2][4];  // [mt][nt pair-of-2? no: nt 0..3] -> use [2][4][4]
    u16 xrr[2][4][4];
#pragma unroll
    for (int mt = 0; mt < 2; ++mt)
#pragma unroll
        for (int r = 0; r < 4; ++r) {
            int row = m0 + mt * 16 + quad * 4 + r;
#pragma unroll
            for (int nt = 0; nt < 4; ++nt)
                xrr[mt][nt][r] = xbf[(size_t)row * 256 + w * 64 + nt * 16 + l16];
        }
    (void)xr;
    if (tid < 128) wl[tid] = wr[(size_t)m0 * 4 + tid];

    auto stageB = [&](int u, int buf) {
        int e = u >> 2, kit = u & 3;
        const u16* Bg = W3T + (size_t)e * 65536;
#pragma unroll
        for (int i = 0; i < 8; ++i) {        // 2048 slots (256 rows x 8 chunks)
            int s = i * 256 + tid, n = s >> 3, c = s & 7;
            gldlds(Bg + (size_t)n * 256 + kit * 64 + ((c ^ (n & 7)) << 3), &Bs[buf][s * 8]);
        }
    };
    uint4 aR[2][2][2];   // [ring][mt][ks]
    auto loadA = [&](int u, int ring) {
        int e = u >> 2, kit = u & 3;
#pragma unroll
        for (int mt = 0; mt < 2; ++mt) {
            const u16* p = h2 + ((size_t)e * 16384 + m0 + mt * 16 + l16) * 256 + kit * 64 + quad * 8;
            aR[ring][mt][0] = *(const uint4*)p;
            aR[ring][mt][1] = *(const uint4*)(p + 16);   // ks=1: +32 elements
        }
    };

    f32x4 oacc[2][4] = {};
    f32x4 acc[2][4] = {};
    stageB(0, 0); loadA(0, 0);
#pragma unroll 4
    for (int u = 0; u < 16; ++u) {
        __syncthreads();
        if (u < 15) { stageB(u + 1, (u + 1) & 1); loadA(u + 1, (u + 1) & 1); }
#pragma unroll
        for (int ks = 0; ks < 2; ++ks) {
#pragma unroll
            for (int nt = 0; nt < 4; ++nt) {
                int n = w * 64 + nt * 16 + l16;
                bf16x8 b = *(const bf16x8*)(&Bs[u & 1][n * 64 + (((ks * 4 + quad) ^ (n & 7)) << 3)]);
#pragma unroll
                for (int mt = 0; mt < 2; ++mt) {
                    union { uint4 u4; bf16x8 v; } av; av.u4 = aR[u & 1][mt][ks];
                    acc[mt][nt] = __builtin_amdgcn_mfma_f32_16x16x32_bf16(av.v, b, acc[mt][nt], 0, 0, 0);
                }
            }
        }
        if ((u & 3) == 3) {
            int e = u >> 2;
            float b3v[4], egv[4], ebv[4];
#pragma unroll
            for (int nt = 0; nt < 4; ++nt) {
                int col = w * 64 + nt * 16 + l16;
                b3v[nt] = b3[e * 256 + col]; egv[nt] = eg[e * 256 + col]; ebv[nt] = eb[e * 256 + col];
            }
#pragma unroll
            for (int mt = 0; mt < 2; ++mt)
#pragma unroll
                for (int r = 0; r < 4; ++r) {
                    int rl = mt * 16 + quad * 4 + r;
                    float ss = 0.f, qq = 0.f;
#pragma unroll
                    for (int nt = 0; nt < 4; ++nt) {
                        float v = acc[mt][nt][r] + b3v[nt] + bf2f(xrr[mt][nt][r]);
                        acc[mt][nt][r] = v;
                        ss += v; qq += v * v;
                    }
#pragma unroll
                    for (int d = 1; d < 16; d <<= 1) { ss += __shfl_xor(ss, d); qq += __shfl_xor(qq, d); }
                    if (l16 == 0) red[w * 32 + rl] = make_float2(ss, qq);
                }
            __syncthreads();
            if (tid < 32) {
                float ss = 0.f, qq = 0.f;
#pragma unroll
                for (int ww = 0; ww < 4; ++ww) { float2 t = red[ww * 32 + tid]; ss += t.x; qq += t.y; }
                float mu = ss * (1.f / 256.f);
                float var = qq * (1.f / 256.f) - mu * mu;
                muv[tid] = mu;
                rsv[tid] = 1.f / sqrtf(var + 1e-5f);
            }
            __syncthreads();
#pragma unroll
            for (int mt = 0; mt < 2; ++mt)
#pragma unroll
                for (int r = 0; r < 4; ++r) {
                    int rl = mt * 16 + quad * 4 + r;
                    float mu = muv[rl], rs = rsv[rl], we = wl[rl * 4 + e];
#pragma unroll
                    for (int nt = 0; nt < 4; ++nt) {
                        float y = (acc[mt][nt][r] - mu) * rs * egv[nt] + ebv[nt];
                        oacc[mt][nt][r] += we * y;
                        acc[mt][nt][r] = 0.f;
                    }
                }
        }
    }
#pragma unroll
    for (int mt = 0; mt < 2; ++mt)
#pragma unroll
        for (int r = 0; r < 4; ++r) {
            int rl = mt * 16 + quad * 4 + r;
#pragma unroll
            for (int nt = 0; nt < 4; ++nt) {
                int col = w * 64 + nt * 16 + l16;
                outp[(size_t)(m0 + rl) * 256 + col] = oacc[mt][nt][r];
            }
        }
}

// ---------------------------------------------------------------------------
extern "C" void kernel_launch(void* const* d_in, const int* in_sizes, int n_in,
                              void* d_out, int out_size, void* d_ws, size_t ws_size,
                              hipStream_t stream) {
    const float* vis   = (const float*)d_in[0];
    const float* lang  = (const float*)d_in[1];
    const float* state = (const float*)d_in[2];
    const float* Wf    = (const float*)d_in[3];
    const float* bf_   = (const float*)d_in[4];
    const float* gf    = (const float*)d_in[5];
    const float* bfln  = (const float*)d_in[6];
    const float* Wg    = (const float*)d_in[7];
    const float* W1    = (const float*)d_in[8];
    const float* b1    = (const float*)d_in[9];
    const float* W2    = (const float*)d_in[10];
    const float* b2    = (const float*)d_in[11];
    const float* W3    = (const float*)d_in[12];
    const float* b3    = (const float*)d_in[13];
    const float* eg    = (const float*)d_in[14];
    const float* eb    = (const float*)d_in[15];
    float* outp = (float*)d_out;

    char* ws = (char*)d_ws;
    size_t off = 0;
    float* lbacc = (float*)(ws + off); off += 256;
    u16* WFT  = (u16*)(ws + off); off += 819200UL;     // WfT [256][1600]
    u16* W1T  = (u16*)(ws + off); off += 1048576UL;    // [E][512][256]
    u16* W2T  = (u16*)(ws + off); off += 1048576UL;    // [E][256][512]
    u16* W3T  = (u16*)(ws + off); off += 524288UL;     // [E][256][256]
    u16* XBF  = (u16*)(ws + off); off += 8388608UL;    // x bf16 [B][256]
    float* WR = (float*)(ws + off); off += 262144UL;   // gate weights [B][4]
    u16* H1   = (u16*)(ws + off); off += 67108864UL;   // [E][B][512]
    u16* H2   = (u16*)(ws + off); off += 33554432UL;   // [E][B][256]
    if (ws_size < off) return;

    int prep_blocks = (PREP_ITEMS + 255) / 256;
    prep_kernel<<<prep_blocks, 256, 0, stream>>>(Wf, W1, W2, W3, WFT, W1T, W2T, W3T, lbacc);
    fusion_kernel<<<512, 256, 0, stream>>>(vis, lang, state, WFT, bf_, gf, bfln, Wg,
                                           XBF, WR, lbacc);
    expert_kernel<4><<<dim3(256, 4, 4), 256, 0, stream>>>(
        XBF, 256, 0L, W1T, 131072L, b1, 512, H1, 512, 8388608L);
    expert_kernel<8><<<dim3(256, 2, 4), 256, 0, stream>>>(
        H1, 512, 8388608L, W2T, 131072L, b2, 256, H2, 256, 4194304L);
    combine_kernel<<<512, 256, 0, stream>>>(H2, W3T, b3, eg, eb, XBF, WR, lbacc, outp);
}

// Round 6
// 336.840 us; speedup vs baseline: 1.5281x; 1.0170x over previous
//
#include <hip/hip_runtime.h>
#include <math.h>

// ---------------------------------------------------------------------------
// FusionMoE R6: every GEMM is an m97 clone — 128x128 block tile, 4 waves of
// 64x64 (acc[4][4], 32 MFMA/wave/kit), BK=64, single-buffered LDS with the
// verified XOR-swizzle layouts, 2 barriers/kit. Fusion uses KSPLIT=5 (bf16
// partials + freduce kernel) to keep grid >= 1280 while cutting B re-reads
// from 512x to 128x. Combine: 64x256 tile, sequential experts.
// ---------------------------------------------------------------------------

typedef unsigned short u16;
typedef unsigned int u32;
typedef __attribute__((ext_vector_type(8))) short bf16x8;
typedef __attribute__((ext_vector_type(4))) float f32x4;

__device__ __forceinline__ float bf2f(u16 u) {
    union { u32 i; float f; } v; v.i = ((u32)u) << 16; return v.f;
}
__device__ __forceinline__ u16 f2bf(float f) {  // RNE
    union { float f; u32 i; } v; v.f = f;
    u32 x = v.i;
    return (u16)((x + 0x7fffu + ((x >> 16) & 1u)) >> 16);
}
__device__ __forceinline__ float gelu_fast(float x) {
    float t = x * (1.59576912f + 0.07135481f * x * x);
    return x / (1.f + __expf(-t));
}
__device__ __forceinline__ u32 pk2(u32 f0, u32 f1) {
    return __builtin_amdgcn_perm(f1, f0, 0x07060302);
}
typedef __attribute__((address_space(1))) void GV;
typedef __attribute__((address_space(3))) void SV;
__device__ __forceinline__ void gldlds(const void* g, void* l) {
    __builtin_amdgcn_global_load_lds((GV*)g, (SV*)l, 16, 0, 0);
}

// ---------------------------------------------------------------------------
// K0: prep — weight transposes to bf16 + lbacc zero
// ---------------------------------------------------------------------------
#define SEG_WF  409600
#define SEG_W1  524288
#define SEG_W2  524288
#define SEG_W3  262144
#define PREP_ITEMS (SEG_WF + SEG_W1 + SEG_W2 + SEG_W3 + 8)

__global__ __launch_bounds__(256) void prep_kernel(
    const float* __restrict__ Wf, const float* __restrict__ W1, const float* __restrict__ W2,
    const float* __restrict__ W3,
    u16* __restrict__ wft, u16* __restrict__ w1t, u16* __restrict__ w2t, u16* __restrict__ w3t,
    float* __restrict__ lbacc) {
    int idx = blockIdx.x * 256 + threadIdx.x;
    if (idx < SEG_WF) {  // WfT[n<256][k<1600] = Wf[k][n]
        int n = idx / 1600, k = idx % 1600;
        wft[idx] = f2bf(Wf[(size_t)k * 256 + n]);
        return;
    }
    idx -= SEG_WF;
    if (idx < SEG_W1) {  // W1T[e][n<512][k<256] = W1[e][k][n]
        int e = idx >> 17, r = idx & 131071;
        int n = r >> 8, k = r & 255;
        w1t[idx] = f2bf(W1[(size_t)e * 131072 + (size_t)k * 512 + n]);
        return;
    }
    idx -= SEG_W1;
    if (idx < SEG_W2) {  // W2T[e][n<256][k<512] = W2[e][k][n]
        int e = idx >> 17, r = idx & 131071;
        int n = r >> 9, k = r & 511;
        w2t[idx] = f2bf(W2[(size_t)e * 131072 + (size_t)k * 256 + n]);
        return;
    }
    idx -= SEG_W2;
    if (idx < SEG_W3) {  // W3T[e][n<256][k<256] = W3[e][k][n]
        int e = idx >> 16, r = idx & 65535;
        int n = r >> 8, k = r & 255;
        w3t[idx] = f2bf(W3[(size_t)e * 65536 + (size_t)k * 256 + n]);
        return;
    }
    idx -= SEG_W3;
    if (idx < 8) lbacc[idx] = 0.0f;
}

// ---------------------------------------------------------------------------
// K1: fusion GEMM — 128x128 tile, KSPLIT=5 (5 kits of BK=64 each), A fp32
// staged+perm-packed, B bf16. Single-buffered, 2 barriers/kit. bf16 partials.
// ---------------------------------------------------------------------------
__global__ __launch_bounds__(256) void fusion_gemm(
    const float* __restrict__ vis, const float* __restrict__ lang, const float* __restrict__ state,
    const u16* __restrict__ BT, u16* __restrict__ part) {
    __shared__ __align__(16) u32 Af[8192];   // 32 KB: 128 m x 64 f32, XOR-16 chunks
    __shared__ __align__(16) u16 Bs[8192];   // 16 KB: 128 n x 64 k, XOR-8 chunks
    int tid = threadIdx.x, w = tid >> 6, lane = tid & 63, quad = lane >> 4, l16 = lane & 15;
    int wm = w >> 1, wn = w & 1;
    int m0 = blockIdx.x * 128, n0 = blockIdx.y * 128, ks0 = blockIdx.z * 5;
    f32x4 acc[4][4] = {};

    for (int kit = 0; kit < 5; ++kit) {
        int kg = ks0 + kit;
        const float* base; int ld, koff;
        if (kg < 12)      { base = vis;   ld = 768; koff = kg * 64; }
        else if (kg < 24) { base = lang;  ld = 768; koff = (kg - 12) * 64; }
        else              { base = state; ld = 64;  koff = 0; }
        __syncthreads();
#pragma unroll
        for (int i = 0; i < 8; ++i) {        // A: 2048 chunks of 16B
            int s = i * 256 + tid, m = s >> 4, c = s & 15;
            gldlds(base + (size_t)(m0 + m) * ld + koff + ((c ^ (m & 15)) << 2), &Af[s * 4]);
        }
#pragma unroll
        for (int i = 0; i < 4; ++i) {        // B: 1024 chunks of 16B
            int s = i * 256 + tid, n = s >> 3, c = s & 7;
            gldlds(BT + (size_t)(n0 + n) * 1600 + kg * 64 + ((c ^ (n & 7)) << 3), &Bs[s * 8]);
        }
        __syncthreads();
#pragma unroll
        for (int ks = 0; ks < 2; ++ks) {
            bf16x8 av[4];
#pragma unroll
            for (int mt = 0; mt < 4; ++mt) {
                int m = wm * 64 + mt * 16 + l16;
                int c0 = ks * 8 + quad * 2;
                const u32* rowp = &Af[m * 64];
                uint4 f0 = *(const uint4*)(rowp + ((c0 ^ (m & 15)) << 2));
                uint4 f1 = *(const uint4*)(rowp + (((c0 + 1) ^ (m & 15)) << 2));
                union { u32 u[4]; bf16x8 v; } pk;
                pk.u[0] = pk2(f0.x, f0.y); pk.u[1] = pk2(f0.z, f0.w);
                pk.u[2] = pk2(f1.x, f1.y); pk.u[3] = pk2(f1.z, f1.w);
                av[mt] = pk.v;
            }
#pragma unroll
            for (int nt = 0; nt < 4; ++nt) {
                int n = wn * 64 + nt * 16 + l16;
                bf16x8 b = *(const bf16x8*)(&Bs[n * 64 + (((ks * 4 + quad) ^ (n & 7)) << 3)]);
#pragma unroll
                for (int mt = 0; mt < 4; ++mt)
                    acc[mt][nt] = __builtin_amdgcn_mfma_f32_16x16x32_bf16(av[mt], b, acc[mt][nt], 0, 0, 0);
            }
        }
    }
    // store bf16 partial [split][row][col]
    u16* pp = part + (size_t)blockIdx.z * 4194304;
#pragma unroll
    for (int mt = 0; mt < 4; ++mt)
#pragma unroll
        for (int r = 0; r < 4; ++r) {
            int row = m0 + wm * 64 + mt * 16 + quad * 4 + r;
#pragma unroll
            for (int nt = 0; nt < 4; ++nt) {
                int col = n0 + wn * 64 + nt * 16 + l16;
                pp[(size_t)row * 256 + col] = f2bf(acc[mt][nt][r]);
            }
        }
}

// ---------------------------------------------------------------------------
// K2: freduce — sum 5 partials + bias -> LN -> GELU -> xbf; fused gate
// (fp32 logits, softmax, top-2, lb atomics). 32 rows/block, 8 lanes/row.
// ---------------------------------------------------------------------------
__global__ __launch_bounds__(256) void freduce_kernel(
    const u16* __restrict__ part, const float* __restrict__ bfv, const float* __restrict__ gf,
    const float* __restrict__ bfln, const float* __restrict__ Wg,
    u16* __restrict__ xbf, float* __restrict__ wr, float* __restrict__ lbacc) {
    __shared__ float sacc[8];
    int tid = threadIdx.x;
    if (tid < 8) sacc[tid] = 0.f;
    __syncthreads();
    int r = tid >> 3, cg = tid & 7;
    int row = blockIdx.x * 32 + r;
    int c0 = cg * 32;
    float x[32] = {};
#pragma unroll
    for (int s = 0; s < 5; ++s) {
        const u16* p = part + (size_t)s * 4194304 + (size_t)row * 256 + c0;
#pragma unroll
        for (int v = 0; v < 4; ++v) {
            uint4 q = *(const uint4*)(p + v * 8);
            u32 wsv[4] = {q.x, q.y, q.z, q.w};
#pragma unroll
            for (int h = 0; h < 4; ++h) {
                x[v * 8 + h * 2]     += bf2f((u16)(wsv[h] & 0xffff));
                x[v * 8 + h * 2 + 1] += bf2f((u16)(wsv[h] >> 16));
            }
        }
    }
    float ss = 0.f, qq = 0.f;
#pragma unroll
    for (int j = 0; j < 32; ++j) {
        x[j] += bfv[c0 + j];
        ss += x[j]; qq += x[j] * x[j];
    }
#pragma unroll
    for (int d = 1; d < 8; d <<= 1) { ss += __shfl_xor(ss, d); qq += __shfl_xor(qq, d); }
    float mu = ss * (1.f / 256.f);
    float var = qq * (1.f / 256.f) - mu * mu;
    float rs = 1.f / sqrtf(var + 1e-5f);
    float p0 = 0.f, p1 = 0.f, p2 = 0.f, p3 = 0.f;
    float g[32];
#pragma unroll
    for (int j = 0; j < 32; ++j) {
        float t = (x[j] - mu) * rs * gf[c0 + j] + bfln[c0 + j];
        float gg = gelu_fast(t);
        g[j] = gg;
        float4 wg = *(const float4*)(Wg + (size_t)(c0 + j) * 4);
        p0 += gg * wg.x; p1 += gg * wg.y; p2 += gg * wg.z; p3 += gg * wg.w;
    }
#pragma unroll
    for (int v = 0; v < 4; ++v) {
        uint4 o;
        o.x = (u32)f2bf(g[v*8+0]) | ((u32)f2bf(g[v*8+1]) << 16);
        o.y = (u32)f2bf(g[v*8+2]) | ((u32)f2bf(g[v*8+3]) << 16);
        o.z = (u32)f2bf(g[v*8+4]) | ((u32)f2bf(g[v*8+5]) << 16);
        o.w = (u32)f2bf(g[v*8+6]) | ((u32)f2bf(g[v*8+7]) << 16);
        *(uint4*)(xbf + (size_t)row * 256 + c0 + v * 8) = o;
    }
#pragma unroll
    for (int d = 1; d < 8; d <<= 1) {
        p0 += __shfl_xor(p0, d); p1 += __shfl_xor(p1, d);
        p2 += __shfl_xor(p2, d); p3 += __shfl_xor(p3, d);
    }
    if (cg == 0) {
        float lg[4] = {p0, p1, p2, p3};
        float mx = fmaxf(fmaxf(lg[0], lg[1]), fmaxf(lg[2], lg[3]));
        float ex[4]; float Z = 0.f;
#pragma unroll
        for (int e = 0; e < 4; ++e) { ex[e] = expf(lg[e] - mx); Z += ex[e]; }
        int i0 = 0; float v0 = lg[0];
#pragma unroll
        for (int e = 1; e < 4; ++e) if (lg[e] > v0) { v0 = lg[e]; i0 = e; }
        int i1 = -1; float v1 = -1e30f;
#pragma unroll
        for (int e = 0; e < 4; ++e) if (e != i0 && lg[e] > v1) { v1 = lg[e]; i1 = e; }
        float t = expf(v1 - v0);
        float wA = 1.f / (1.f + t), wB = t / (1.f + t);
        float w4[4] = {0.f, 0.f, 0.f, 0.f};
        w4[i0] = wA; w4[i1] = wB;
#pragma unroll
        for (int e = 0; e < 4; ++e) wr[(size_t)row * 4 + e] = w4[e];
#pragma unroll
        for (int e = 0; e < 4; ++e) atomicAdd(&sacc[e], ex[e] / Z);
        atomicAdd(&sacc[4 + i0], 1.f);
        atomicAdd(&sacc[4 + i1], 1.f);
    }
    __syncthreads();
    if (tid < 8) atomicAdd(lbacc + tid, sacc[tid]);
}

// ---------------------------------------------------------------------------
// K3/K4: expert GEMM + bias + GELU. 128x128 tile, BK=64, single-buffered,
// 2 barriers/kit (m97 pattern).
// ---------------------------------------------------------------------------
template<int KITS>
__global__ __launch_bounds__(256) void expert_kernel(
    const u16* __restrict__ A, int lda, long aE,
    const u16* __restrict__ BT, long bE,
    const float* __restrict__ bias, int biasE,
    u16* __restrict__ outp, int ldo, long oE) {
    __shared__ __align__(16) u16 As[8192];   // 16 KB: 128 m x 64 k
    __shared__ __align__(16) u16 Bs[8192];   // 16 KB: 128 n x 64 k
    int tid = threadIdx.x, w = tid >> 6, lane = tid & 63, quad = lane >> 4, l16 = lane & 15;
    int wm = w >> 1, wn = w & 1;
    int m0 = blockIdx.x * 128, n0 = blockIdx.y * 128;
    int e = blockIdx.z;
    const u16* Ag = A + (size_t)e * aE + (size_t)m0 * lda;
    const u16* Bg = BT + (size_t)e * bE + (size_t)n0 * lda;
    f32x4 acc[4][4] = {};

    for (int kit = 0; kit < KITS; ++kit) {
        __syncthreads();
#pragma unroll
        for (int i = 0; i < 4; ++i) {
            int s = i * 256 + tid, m = s >> 3, c = s & 7;
            gldlds(Ag + (size_t)m * lda + kit * 64 + ((c ^ (m & 7)) << 3), &As[s * 8]);
        }
#pragma unroll
        for (int i = 0; i < 4; ++i) {
            int s = i * 256 + tid, n = s >> 3, c = s & 7;
            gldlds(Bg + (size_t)n * lda + kit * 64 + ((c ^ (n & 7)) << 3), &Bs[s * 8]);
        }
        __syncthreads();
#pragma unroll
        for (int ks = 0; ks < 2; ++ks) {
            bf16x8 av[4];
#pragma unroll
            for (int mt = 0; mt < 4; ++mt) {
                int m = wm * 64 + mt * 16 + l16;
                av[mt] = *(const bf16x8*)(&As[m * 64 + (((ks * 4 + quad) ^ (m & 7)) << 3)]);
            }
#pragma unroll
            for (int nt = 0; nt < 4; ++nt) {
                int n = wn * 64 + nt * 16 + l16;
                bf16x8 b = *(const bf16x8*)(&Bs[n * 64 + (((ks * 4 + quad) ^ (n & 7)) << 3)]);
#pragma unroll
                for (int mt = 0; mt < 4; ++mt)
                    acc[mt][nt] = __builtin_amdgcn_mfma_f32_16x16x32_bf16(av[mt], b, acc[mt][nt], 0, 0, 0);
            }
        }
    }
#pragma unroll
    for (int nt = 0; nt < 4; ++nt) {
        int col = n0 + wn * 64 + nt * 16 + l16;
        float bvv = bias[e * biasE + col];
#pragma unroll
        for (int mt = 0; mt < 4; ++mt)
#pragma unroll
            for (int r = 0; r < 4; ++r) {
                int row = m0 + wm * 64 + mt * 16 + quad * 4 + r;
                outp[(size_t)e * oE + (size_t)row * ldo + col] = f2bf(gelu_fast(acc[mt][nt][r] + bvv));
            }
    }
}

// ---------------------------------------------------------------------------
// K5: combine — 64x256 tile (full row -> local LN), 4 waves of 64x64,
// sequential experts: h2_e@W3_e + b3 + x -> LN -> *eg+eb -> oacc += we*y.
// ---------------------------------------------------------------------------
__global__ __launch_bounds__(256) void combine_kernel(
    const u16* __restrict__ h2, const u16* __restrict__ W3T,
    const float* __restrict__ b3, const float* __restrict__ eg, const float* __restrict__ eb,
    const u16* __restrict__ xbf, const float* __restrict__ wr,
    const float* __restrict__ lbacc, float* __restrict__ outp) {
    __shared__ __align__(16) u16 As[4096];    // 8 KB: 64 m x 64 k
    __shared__ __align__(16) u16 Bs[16384];   // 32 KB: 256 n x 64 k
    __shared__ float wl[256];
    __shared__ float2 red[256];
    __shared__ float muv[64], rsv[64];
    int tid = threadIdx.x, w = tid >> 6, lane = tid & 63, quad = lane >> 4, l16 = lane & 15;
    int m0 = blockIdx.x * 64;
    if (blockIdx.x == 0 && tid == 0) {
        float lb = 0.f;
#pragma unroll
        for (int e = 0; e < 4; ++e)
            lb += (lbacc[4 + e] / 32768.f) * (lbacc[e] / 16384.f);
        outp[4194304] = 4.f * lb;
    }
    // residual x in registers (C-layout) + gate weights
    u16 xrr[4][4][4];
#pragma unroll
    for (int mt = 0; mt < 4; ++mt)
#pragma unroll
        for (int r = 0; r < 4; ++r) {
            int row = m0 + mt * 16 + quad * 4 + r;
#pragma unroll
            for (int nt = 0; nt < 4; ++nt)
                xrr[mt][nt][r] = xbf[(size_t)row * 256 + w * 64 + nt * 16 + l16];
        }
    wl[tid] = wr[(size_t)m0 * 4 + tid];

    f32x4 oacc[4][4] = {};
#pragma unroll 1
    for (int e = 0; e < 4; ++e) {
        const u16* Ag = h2 + ((size_t)e * 16384 + m0) * 256;
        const u16* Bg = W3T + (size_t)e * 65536;
        f32x4 acc[4][4] = {};
        for (int kit = 0; kit < 4; ++kit) {
            __syncthreads();
#pragma unroll
            for (int i = 0; i < 2; ++i) {     // A: 512 chunks
                int s = i * 256 + tid, m = s >> 3, c = s & 7;
                gldlds(Ag + (size_t)m * 256 + kit * 64 + ((c ^ (m & 7)) << 3), &As[s * 8]);
            }
#pragma unroll
            for (int i = 0; i < 8; ++i) {     // B: 2048 chunks
                int s = i * 256 + tid, n = s >> 3, c = s & 7;
                gldlds(Bg + (size_t)n * 256 + kit * 64 + ((c ^ (n & 7)) << 3), &Bs[s * 8]);
            }
            __syncthreads();
#pragma unroll
            for (int ks = 0; ks < 2; ++ks) {
                bf16x8 av[4];
#pragma unroll
                for (int mt = 0; mt < 4; ++mt) {
                    int m = mt * 16 + l16;
                    av[mt] = *(const bf16x8*)(&As[m * 64 + (((ks * 4 + quad) ^ (m & 7)) << 3)]);
                }
#pragma unroll
                for (int nt = 0; nt < 4; ++nt) {
                    int n = w * 64 + nt * 16 + l16;
                    bf16x8 b = *(const bf16x8*)(&Bs[n * 64 + (((ks * 4 + quad) ^ (n & 7)) << 3)]);
#pragma unroll
                    for (int mt = 0; mt < 4; ++mt)
                        acc[mt][nt] = __builtin_amdgcn_mfma_f32_16x16x32_bf16(av[mt], b, acc[mt][nt], 0, 0, 0);
                }
            }
        }
        float b3v[4], egv[4], ebv[4];
#pragma unroll
        for (int nt = 0; nt < 4; ++nt) {
            int col = w * 64 + nt * 16 + l16;
            b3v[nt] = b3[e * 256 + col]; egv[nt] = eg[e * 256 + col]; ebv[nt] = eb[e * 256 + col];
        }
#pragma unroll
        for (int mt = 0; mt < 4; ++mt)
#pragma unroll
            for (int r = 0; r < 4; ++r) {
                int rl = mt * 16 + quad * 4 + r;
                float ss = 0.f, qq = 0.f;
#pragma unroll
                for (int nt = 0; nt < 4; ++nt) {
                    float v = acc[mt][nt][r] + b3v[nt] + bf2f(xrr[mt][nt][r]);
                    acc[mt][nt][r] = v;
                    ss += v; qq += v * v;
                }
#pragma unroll
                for (int d = 1; d < 16; d <<= 1) { ss += __shfl_xor(ss, d); qq += __shfl_xor(qq, d); }
                if (l16 == 0) red[w * 64 + rl] = make_float2(ss, qq);
            }
        __syncthreads();
        if (tid < 64) {
            float ss = 0.f, qq = 0.f;
#pragma unroll
            for (int ww = 0; ww < 4; ++ww) { float2 t = red[ww * 64 + tid]; ss += t.x; qq += t.y; }
            float mu = ss * (1.f / 256.f);
            float var = qq * (1.f / 256.f) - mu * mu;
            muv[tid] = mu;
            rsv[tid] = 1.f / sqrtf(var + 1e-5f);
        }
        __syncthreads();
#pragma unroll
        for (int mt = 0; mt < 4; ++mt)
#pragma unroll
            for (int r = 0; r < 4; ++r) {
                int rl = mt * 16 + quad * 4 + r;
                float mu = muv[rl], rs = rsv[rl], we = wl[rl * 4 + e];
#pragma unroll
                for (int nt = 0; nt < 4; ++nt) {
                    float y = (acc[mt][nt][r] - mu) * rs * egv[nt] + ebv[nt];
                    oacc[mt][nt][r] += we * y;
                }
            }
    }
#pragma unroll
    for (int mt = 0; mt < 4; ++mt)
#pragma unroll
        for (int r = 0; r < 4; ++r) {
            int rl = mt * 16 + quad * 4 + r;
#pragma unroll
            for (int nt = 0; nt < 4; ++nt) {
                int col = w * 64 + nt * 16 + l16;
                outp[(size_t)(m0 + rl) * 256 + col] = oacc[mt][nt][r];
            }
        }
}

// ---------------------------------------------------------------------------
extern "C" void kernel_launch(void* const* d_in, const int* in_sizes, int n_in,
                              void* d_out, int out_size, void* d_ws, size_t ws_size,
                              hipStream_t stream) {
    const float* vis   = (const float*)d_in[0];
    const float* lang  = (const float*)d_in[1];
    const float* state = (const float*)d_in[2];
    const float* Wf    = (const float*)d_in[3];
    const float* bf_   = (const float*)d_in[4];
    const float* gf    = (const float*)d_in[5];
    const float* bfln  = (const float*)d_in[6];
    const float* Wg    = (const float*)d_in[7];
    const float* W1    = (const float*)d_in[8];
    const float* b1    = (const float*)d_in[9];
    const float* W2    = (const float*)d_in[10];
    const float* b2    = (const float*)d_in[11];
    const float* W3    = (const float*)d_in[12];
    const float* b3    = (const float*)d_in[13];
    const float* eg    = (const float*)d_in[14];
    const float* eb    = (const float*)d_in[15];
    float* outp = (float*)d_out;

    char* ws = (char*)d_ws;
    size_t off = 0;
    float* lbacc = (float*)(ws + off); off += 256;
    u16* WFT  = (u16*)(ws + off); off += 819200UL;     // WfT [256][1600]
    u16* W1T  = (u16*)(ws + off); off += 1048576UL;    // [E][512][256]
    u16* W2T  = (u16*)(ws + off); off += 1048576UL;    // [E][256][512]
    u16* W3T  = (u16*)(ws + off); off += 524288UL;     // [E][256][256]
    u16* XBF  = (u16*)(ws + off); off += 8388608UL;    // x bf16 [B][256]
    float* WR = (float*)(ws + off); off += 262144UL;   // gate weights [B][4]
    u16* H1   = (u16*)(ws + off); off += 67108864UL;   // [E][B][512]
    u16* H2   = (u16*)(ws + off); off += 33554432UL;   // [E][B][256]
    u16* PART = (u16*)(ws + off); off += 41943040UL;   // [5][B][256] bf16 partials
    if (ws_size < off) return;

    int prep_blocks = (PREP_ITEMS + 255) / 256;
    prep_kernel<<<prep_blocks, 256, 0, stream>>>(Wf, W1, W2, W3, WFT, W1T, W2T, W3T, lbacc);
    fusion_gemm<<<dim3(128, 2, 5), 256, 0, stream>>>(vis, lang, state, WFT, PART);
    freduce_kernel<<<512, 256, 0, stream>>>(PART, bf_, gf, bfln, Wg, XBF, WR, lbacc);
    expert_kernel<4><<<dim3(128, 4, 4), 256, 0, stream>>>(
        XBF, 256, 0L, W1T, 131072L, b1, 512, H1, 512, 8388608L);
    expert_kernel<8><<<dim3(128, 2, 4), 256, 0, stream>>>(
        H1, 512, 8388608L, W2T, 131072L, b2, 256, H2, 256, 4194304L);
    combine_kernel<<<256, 256, 0, stream>>>(H2, W3T, b3, eg, eb, XBF, WR, lbacc, outp);
}